// Round 1
// baseline (1793.948 us; speedup 1.0000x reference)
//
#include <hip/hip_runtime.h>
#include <math.h>

// Problem constants
constexpr int Bb = 4;
constexpr int SQn = 2048;
constexpr int SKn = 2048;
constexpr int Dd  = 1024;

constexpr int TS = 64;   // output tile (64x64 per block)
constexpr int KS = 16;   // K-step

// C[m,n] = sum_k A[m,k] * W[n,k] (+ bias[n])   -- "NT" gemm (row . row)
template<bool HAS_BIAS>
__global__ __launch_bounds__(256)
void gemm_nt(const float* __restrict__ A, const float* __restrict__ W,
             const float* __restrict__ bias, float* __restrict__ C,
             int M, int N, int K)
{
    __shared__ float As[KS][TS];
    __shared__ float Ws[KS][TS];
    const int tid = threadIdx.x;
    const int m0 = blockIdx.y * TS;
    const int n0 = blockIdx.x * TS;
    const int lr = tid >> 2;          // 0..63 : row within tile for loading
    const int lc = (tid & 3) << 2;    // 0,4,8,12 : k-offset (float4)
    const int tx = tid & 15;          // output col group
    const int ty = tid >> 4;          // output row group

    float acc[4][4] = {};

    for (int k0 = 0; k0 < K; k0 += KS) {
        float4 av = *(const float4*)(A + (size_t)(m0 + lr) * K + (k0 + lc));
        float4 wv = *(const float4*)(W + (size_t)(n0 + lr) * K + (k0 + lc));
        __syncthreads();
        As[lc + 0][lr] = av.x; As[lc + 1][lr] = av.y;
        As[lc + 2][lr] = av.z; As[lc + 3][lr] = av.w;
        Ws[lc + 0][lr] = wv.x; Ws[lc + 1][lr] = wv.y;
        Ws[lc + 2][lr] = wv.z; Ws[lc + 3][lr] = wv.w;
        __syncthreads();
#pragma unroll
        for (int kk = 0; kk < KS; ++kk) {
            float a[4], b[4];
            *(float4*)a = *(const float4*)(&As[kk][ty << 2]);
            *(float4*)b = *(const float4*)(&Ws[kk][tx << 2]);
#pragma unroll
            for (int i = 0; i < 4; ++i)
#pragma unroll
                for (int j = 0; j < 4; ++j)
                    acc[i][j] += a[i] * b[j];
        }
    }

#pragma unroll
    for (int i = 0; i < 4; ++i) {
        const int m = m0 + (ty << 2) + i;
        const int n = n0 + (tx << 2);
        float4 o;
        o.x = acc[i][0]; o.y = acc[i][1]; o.z = acc[i][2]; o.w = acc[i][3];
        if (HAS_BIAS) {
            o.x += bias[n + 0]; o.y += bias[n + 1];
            o.z += bias[n + 2]; o.w += bias[n + 3];
        }
        *(float4*)(C + (size_t)m * N + n) = o;
    }
}

// C[m,n] = sum_k A[m,k] * B[k,n]   -- "NN" gemm (for P @ V)
__global__ __launch_bounds__(256)
void gemm_nn(const float* __restrict__ A, const float* __restrict__ Bm,
             float* __restrict__ C, int M, int N, int K)
{
    __shared__ float As[KS][TS];
    __shared__ float Bs[KS][TS];
    const int tid = threadIdx.x;
    const int m0 = blockIdx.y * TS;
    const int n0 = blockIdx.x * TS;
    const int lr = tid >> 2;          // A-load row 0..63
    const int lc = (tid & 3) << 2;    // A-load k-offset
    const int br = tid >> 4;          // B-load k row 0..15
    const int bc = (tid & 15) << 2;   // B-load col offset 0..60
    const int tx = tid & 15;
    const int ty = tid >> 4;

    float acc[4][4] = {};

    for (int k0 = 0; k0 < K; k0 += KS) {
        float4 av = *(const float4*)(A + (size_t)(m0 + lr) * K + (k0 + lc));
        float4 bv = *(const float4*)(Bm + (size_t)(k0 + br) * N + (n0 + bc));
        __syncthreads();
        As[lc + 0][lr] = av.x; As[lc + 1][lr] = av.y;
        As[lc + 2][lr] = av.z; As[lc + 3][lr] = av.w;
        *(float4*)(&Bs[br][bc]) = bv;
        __syncthreads();
#pragma unroll
        for (int kk = 0; kk < KS; ++kk) {
            float a[4], b[4];
            *(float4*)a = *(const float4*)(&As[kk][ty << 2]);
            *(float4*)b = *(const float4*)(&Bs[kk][tx << 2]);
#pragma unroll
            for (int i = 0; i < 4; ++i)
#pragma unroll
                for (int j = 0; j < 4; ++j)
                    acc[i][j] += a[i] * b[j];
        }
    }

#pragma unroll
    for (int i = 0; i < 4; ++i) {
        const int m = m0 + (ty << 2) + i;
        const int n = n0 + (tx << 2);
        float4 o;
        o.x = acc[i][0]; o.y = acc[i][1]; o.z = acc[i][2]; o.w = acc[i][3];
        *(float4*)(C + (size_t)m * N + n) = o;
    }
}

// Row-wise softmax in place. One block (256 threads) per row.
__global__ __launch_bounds__(256)
void softmax_rows(float* __restrict__ S, int ncols)
{
    __shared__ float red[8];
    const int tid = threadIdx.x;
    float* p = S + (size_t)blockIdx.x * ncols;

    float lmax = -3.4e38f;
    for (int i = tid * 4; i < ncols; i += 1024) {
        float4 v = *(const float4*)(p + i);
        lmax = fmaxf(lmax, fmaxf(fmaxf(v.x, v.y), fmaxf(v.z, v.w)));
    }
#pragma unroll
    for (int o = 32; o > 0; o >>= 1) lmax = fmaxf(lmax, __shfl_down(lmax, o));
    if ((tid & 63) == 0) red[tid >> 6] = lmax;
    __syncthreads();
    const float rmax = fmaxf(fmaxf(red[0], red[1]), fmaxf(red[2], red[3]));

    float lsum = 0.f;
    for (int i = tid * 4; i < ncols; i += 1024) {
        float4 v = *(const float4*)(p + i);
        v.x = __expf(v.x - rmax); v.y = __expf(v.y - rmax);
        v.z = __expf(v.z - rmax); v.w = __expf(v.w - rmax);
        lsum += (v.x + v.y) + (v.z + v.w);
        *(float4*)(p + i) = v;
    }
#pragma unroll
    for (int o = 32; o > 0; o >>= 1) lsum += __shfl_down(lsum, o);
    if ((tid & 63) == 0) red[4 + (tid >> 6)] = lsum;
    __syncthreads();
    const float inv = 1.f / (((red[4] + red[5]) + (red[6] + red[7])));

    for (int i = tid * 4; i < ncols; i += 1024) {
        float4 v = *(const float4*)(p + i);
        v.x *= inv; v.y *= inv; v.z *= inv; v.w *= inv;
        *(float4*)(p + i) = v;
    }
}

extern "C" void kernel_launch(void* const* d_in, const int* in_sizes, int n_in,
                              void* d_out, int out_size, void* d_ws, size_t ws_size,
                              hipStream_t stream)
{
    const float* x  = (const float*)d_in[0];  // [B,SQ,D]
    const float* c  = (const float*)d_in[1];  // [B,SK,D]
    const float* Wq = (const float*)d_in[2];
    const float* bq = (const float*)d_in[3];
    const float* Wk = (const float*)d_in[4];
    const float* bk = (const float*)d_in[5];
    const float* Wv = (const float*)d_in[6];
    const float* bv = (const float*)d_in[7];
    float* out = (float*)d_out;

    float* Q  = (float*)d_ws;                       // [B*SQ, D]
    float* Kp = Q  + (size_t)Bb * SQn * Dd;         // [B*SK, D]
    float* Vp = Kp + (size_t)Bb * SKn * Dd;         // [B*SK, D]
    float* S  = Vp + (size_t)Bb * SKn * Dd;         // [SQ, SK] (per-batch reuse)

    const dim3 blk(256);

    // Projections: treat [B,S,D] as [B*S, D]
    {
        dim3 g(Dd / TS, (Bb * SQn) / TS, 1);
        gemm_nt<true><<<g, blk, 0, stream>>>(x, Wq, bq, Q,  Bb * SQn, Dd, Dd);
        gemm_nt<true><<<g, blk, 0, stream>>>(c, Wk, bk, Kp, Bb * SKn, Dd, Dd);
        gemm_nt<true><<<g, blk, 0, stream>>>(c, Wv, bv, Vp, Bb * SKn, Dd, Dd);
    }

    for (int b = 0; b < Bb; ++b) {
        const float* Qb = Q  + (size_t)b * SQn * Dd;
        const float* Kb = Kp + (size_t)b * SKn * Dd;
        const float* Vb = Vp + (size_t)b * SKn * Dd;
        float*       Ob = out + (size_t)b * SQn * Dd;

        dim3 gs(SKn / TS, SQn / TS, 1);
        gemm_nt<false><<<gs, blk, 0, stream>>>(Qb, Kb, nullptr, S, SQn, SKn, Dd);

        softmax_rows<<<dim3(SQn), blk, 0, stream>>>(S, SKn);

        dim3 gp(Dd / TS, SQn / TS, 1);
        gemm_nn<<<gp, blk, 0, stream>>>(S, Vb, Ob, SQn, Dd, SKn);
    }
}

// Round 2
// 1085.174 us; speedup vs baseline: 1.6531x; 1.6531x over previous
//
#include <hip/hip_runtime.h>

using f32x4  = __attribute__((ext_vector_type(4))) float;
using bf16x8 = __attribute__((ext_vector_type(8))) __bf16;
using u16x4  = __attribute__((ext_vector_type(4))) unsigned short;

constexpr int Bb = 4, SQn = 2048, SKn = 2048, Dd = 1024;
constexpr int BM = 128, BN = 128, BK = 32;

__device__ __forceinline__ unsigned fbitsu(float x){ union{float f;unsigned u;}c; c.f=x; return c.u; }
__device__ __forceinline__ float ubitsf(unsigned u){ union{unsigned u;float f;}c; c.u=u; return c.f; }
__device__ __forceinline__ unsigned short hi_trunc(float x){ return (unsigned short)(fbitsu(x)>>16); }
__device__ __forceinline__ unsigned short hi_rne(float x){ unsigned u=fbitsu(x); return (unsigned short)((u + 0x7FFFu + ((u>>16)&1u))>>16); }
__device__ __forceinline__ float from_hi(unsigned short h){ return ubitsf(((unsigned)h)<<16); }

__device__ __forceinline__ f32x4 mfma_bf16(bf16x8 a, bf16x8 b, f32x4 c){
    return __builtin_amdgcn_mfma_f32_16x16x32_bf16(a, b, c, 0, 0, 0);
}

// ---------------------------------------------------------------------------
// Projection GEMM: C = A[M,K] . B[N,K]^T + bias, fp32 sources, reg-converted
// to bf16 hi/lo in LDS. TERMS=3: hi*hi + hi*lo + lo*hi (fp32-like precision).
// EPI=0: write split bf16 (O0=hi, O1=lo) row-major [M,N].
// EPI=1: write bf16 transposed per batch: O0[b][col][t], b=row>>11, t=row&2047.
// ---------------------------------------------------------------------------
template<int TERMS, int EPI>
__global__ __launch_bounds__(256, 2)
void gemm_proj(const float* __restrict__ A, const float* __restrict__ Bm,
               const float* __restrict__ bias,
               unsigned short* __restrict__ O0, unsigned short* __restrict__ O1,
               int M, int N, int K)
{
    __shared__ __align__(16) unsigned short Ash[BM*BK], Bsh[BN*BK];
    __shared__ __align__(16) unsigned short Asl[TERMS==3?BM*BK:8], Bsl[TERMS==3?BN*BK:8];

    const int tid  = threadIdx.x;
    const int lane = tid & 63;
    const int w    = tid >> 6;
    const int wr   = (w >> 1) * 64, wc = (w & 1) * 64;
    const int lr   = lane & 15, lg = lane >> 4;
    const int m0   = blockIdx.y * BM, n0 = blockIdx.x * BN;

    f32x4 acc[4][4] = {};

    for (int k0 = 0; k0 < K; k0 += BK) {
        float4 av[4], bv[4];
#pragma unroll
        for (int u = 0; u < 4; ++u) {
            const int f = u*256 + tid;
            const int row = f >> 3, ko = (f & 7) << 2;
            av[u] = *(const float4*)(A  + (size_t)(m0+row)*K + k0 + ko);
            bv[u] = *(const float4*)(Bm + (size_t)(n0+row)*K + k0 + ko);
        }
        __syncthreads();
#pragma unroll
        for (int u = 0; u < 4; ++u) {
            const int f = u*256 + tid;
            const int row = f >> 3, ko = (f & 7) << 2;
            float a4[4], b4[4];
            *(float4*)a4 = av[u]; *(float4*)b4 = bv[u];
            u16x4 ah, bh;
            if (TERMS == 3) {
                u16x4 al, bl;
#pragma unroll
                for (int j = 0; j < 4; ++j) {
                    ah[j] = hi_trunc(a4[j]); al[j] = hi_trunc(a4[j] - from_hi(ah[j]));
                    bh[j] = hi_trunc(b4[j]); bl[j] = hi_trunc(b4[j] - from_hi(bh[j]));
                }
                *(u16x4*)&Asl[row*BK + ko] = al;
                *(u16x4*)&Bsl[row*BK + ko] = bl;
            } else {
#pragma unroll
                for (int j = 0; j < 4; ++j) { ah[j] = hi_rne(a4[j]); bh[j] = hi_rne(b4[j]); }
            }
            *(u16x4*)&Ash[row*BK + ko] = ah;
            *(u16x4*)&Bsh[row*BK + ko] = bh;
        }
        __syncthreads();

        bf16x8 afh[4], bfh[4];
#pragma unroll
        for (int i = 0; i < 4; ++i) {
            afh[i] = *(const bf16x8*)&Ash[(wr + i*16 + lr)*BK + lg*8];
            bfh[i] = *(const bf16x8*)&Bsh[(wc + i*16 + lr)*BK + lg*8];
        }
        if (TERMS == 3) {
            bf16x8 afl[4], bfl[4];
#pragma unroll
            for (int i = 0; i < 4; ++i) {
                afl[i] = *(const bf16x8*)&Asl[(wr + i*16 + lr)*BK + lg*8];
                bfl[i] = *(const bf16x8*)&Bsl[(wc + i*16 + lr)*BK + lg*8];
            }
#pragma unroll
            for (int i = 0; i < 4; ++i)
#pragma unroll
                for (int j = 0; j < 4; ++j) {
                    acc[i][j] = mfma_bf16(afh[i], bfh[j], acc[i][j]);
                    acc[i][j] = mfma_bf16(afh[i], bfl[j], acc[i][j]);
                    acc[i][j] = mfma_bf16(afl[i], bfh[j], acc[i][j]);
                }
        } else {
#pragma unroll
            for (int i = 0; i < 4; ++i)
#pragma unroll
                for (int j = 0; j < 4; ++j)
                    acc[i][j] = mfma_bf16(afh[i], bfh[j], acc[i][j]);
        }
    }

#pragma unroll
    for (int j = 0; j < 4; ++j) {
        const int col = n0 + wc + j*16 + lr;
        const float bc = bias[col];
#pragma unroll
        for (int i = 0; i < 4; ++i) {
            if (EPI == 0) {
#pragma unroll
                for (int r = 0; r < 4; ++r) {
                    const int row = m0 + wr + i*16 + lg*4 + r;
                    const float v = acc[i][j][r] + bc;
                    const unsigned short h = hi_trunc(v);
                    O0[(size_t)row*N + col] = h;
                    O1[(size_t)row*N + col] = hi_trunc(v - from_hi(h));
                }
            } else {
                const int row0 = m0 + wr + i*16 + lg*4;
                const int b = row0 >> 11, t0 = row0 & 2047;
                u16x4 pk;
#pragma unroll
                for (int r = 0; r < 4; ++r) pk[r] = hi_rne(acc[i][j][r] + bc);
                *(u16x4*)&O0[(((size_t)b*Dd + col) << 11) + t0] = pk;
            }
        }
    }
}

// ---------------------------------------------------------------------------
// bf16-source NT GEMM: C[M,N] = A[M,K] . B[N,K]^T, fp32 out.
// TERMS=3: A = Ah+Al, B = Bh+Bl (split). TERMS=1: plain.
// ---------------------------------------------------------------------------
template<int TERMS>
__global__ __launch_bounds__(256, 2)
void gemm_bf16k(const unsigned short* __restrict__ Ahg, const unsigned short* __restrict__ Alg,
                const unsigned short* __restrict__ Bhg, const unsigned short* __restrict__ Blg,
                float* __restrict__ Cout, int M, int N, int K)
{
    __shared__ __align__(16) unsigned short Ash[BM*BK], Bsh[BN*BK];
    __shared__ __align__(16) unsigned short Asl[TERMS==3?BM*BK:8], Bsl[TERMS==3?BN*BK:8];

    const int tid  = threadIdx.x;
    const int lane = tid & 63;
    const int w    = tid >> 6;
    const int wr   = (w >> 1) * 64, wc = (w & 1) * 64;
    const int lr   = lane & 15, lg = lane >> 4;
    const int m0   = blockIdx.y * BM, n0 = blockIdx.x * BN;

    f32x4 acc[4][4] = {};

    for (int k0 = 0; k0 < K; k0 += BK) {
        float4 ra[2], rb[2], ral[2], rbl[2];
#pragma unroll
        for (int u = 0; u < 2; ++u) {
            const int f = u*256 + tid;
            const int row = f >> 2, ko = (f & 3) << 3;
            ra[u] = *(const float4*)(Ahg + (size_t)(m0+row)*K + k0 + ko);
            rb[u] = *(const float4*)(Bhg + (size_t)(n0+row)*K + k0 + ko);
            if (TERMS == 3) {
                ral[u] = *(const float4*)(Alg + (size_t)(m0+row)*K + k0 + ko);
                rbl[u] = *(const float4*)(Blg + (size_t)(n0+row)*K + k0 + ko);
            }
        }
        __syncthreads();
#pragma unroll
        for (int u = 0; u < 2; ++u) {
            const int f = u*256 + tid;
            const int row = f >> 2, ko = (f & 3) << 3;
            *(float4*)&Ash[row*BK + ko] = ra[u];
            *(float4*)&Bsh[row*BK + ko] = rb[u];
            if (TERMS == 3) {
                *(float4*)&Asl[row*BK + ko] = ral[u];
                *(float4*)&Bsl[row*BK + ko] = rbl[u];
            }
        }
        __syncthreads();

        bf16x8 afh[4], bfh[4];
#pragma unroll
        for (int i = 0; i < 4; ++i) {
            afh[i] = *(const bf16x8*)&Ash[(wr + i*16 + lr)*BK + lg*8];
            bfh[i] = *(const bf16x8*)&Bsh[(wc + i*16 + lr)*BK + lg*8];
        }
        if (TERMS == 3) {
            bf16x8 afl[4], bfl[4];
#pragma unroll
            for (int i = 0; i < 4; ++i) {
                afl[i] = *(const bf16x8*)&Asl[(wr + i*16 + lr)*BK + lg*8];
                bfl[i] = *(const bf16x8*)&Bsl[(wc + i*16 + lr)*BK + lg*8];
            }
#pragma unroll
            for (int i = 0; i < 4; ++i)
#pragma unroll
                for (int j = 0; j < 4; ++j) {
                    acc[i][j] = mfma_bf16(afh[i], bfh[j], acc[i][j]);
                    acc[i][j] = mfma_bf16(afh[i], bfl[j], acc[i][j]);
                    acc[i][j] = mfma_bf16(afl[i], bfh[j], acc[i][j]);
                }
        } else {
#pragma unroll
            for (int i = 0; i < 4; ++i)
#pragma unroll
                for (int j = 0; j < 4; ++j)
                    acc[i][j] = mfma_bf16(afh[i], bfh[j], acc[i][j]);
        }
    }

#pragma unroll
    for (int j = 0; j < 4; ++j) {
        const int col = n0 + wc + j*16 + lr;
#pragma unroll
        for (int i = 0; i < 4; ++i) {
#pragma unroll
            for (int r = 0; r < 4; ++r) {
                const int row = m0 + wr + i*16 + lg*4 + r;
                Cout[(size_t)row*N + col] = acc[i][j][r];
            }
        }
    }
}

// ---------------------------------------------------------------------------
// Row softmax (2048 cols), fp32 in -> bf16 out. One 256-thread block per row.
// ---------------------------------------------------------------------------
__global__ __launch_bounds__(256)
void softmax_p(const float* __restrict__ S, unsigned short* __restrict__ P)
{
    const int tid = threadIdx.x;
    const float* p = S + (size_t)blockIdx.x * SKn;
    unsigned short* o = P + (size_t)blockIdx.x * SKn;
    __shared__ float red[8];

    float4 v0 = *(const float4*)(p + tid*4);
    float4 v1 = *(const float4*)(p + 1024 + tid*4);
    float m = fmaxf(fmaxf(fmaxf(v0.x,v0.y),fmaxf(v0.z,v0.w)),
                    fmaxf(fmaxf(v1.x,v1.y),fmaxf(v1.z,v1.w)));
#pragma unroll
    for (int o2 = 32; o2 > 0; o2 >>= 1) m = fmaxf(m, __shfl_down(m, o2));
    if ((tid & 63) == 0) red[tid >> 6] = m;
    __syncthreads();
    m = fmaxf(fmaxf(red[0],red[1]), fmaxf(red[2],red[3]));

    float e[8];
    e[0]=__expf(v0.x-m); e[1]=__expf(v0.y-m); e[2]=__expf(v0.z-m); e[3]=__expf(v0.w-m);
    e[4]=__expf(v1.x-m); e[5]=__expf(v1.y-m); e[6]=__expf(v1.z-m); e[7]=__expf(v1.w-m);
    float s = ((e[0]+e[1])+(e[2]+e[3])) + ((e[4]+e[5])+(e[6]+e[7]));
#pragma unroll
    for (int o2 = 32; o2 > 0; o2 >>= 1) s += __shfl_down(s, o2);
    if ((tid & 63) == 0) red[4 + (tid >> 6)] = s;
    __syncthreads();
    const float inv = 1.f / ((red[4]+red[5])+(red[6]+red[7]));

    u16x4 p0, p1;
#pragma unroll
    for (int r = 0; r < 4; ++r) { p0[r] = hi_rne(e[r]*inv); p1[r] = hi_rne(e[4+r]*inv); }
    *(u16x4*)&o[tid*4] = p0;
    *(u16x4*)&o[1024 + tid*4] = p1;
}

extern "C" void kernel_launch(void* const* d_in, const int* in_sizes, int n_in,
                              void* d_out, int out_size, void* d_ws, size_t ws_size,
                              hipStream_t stream)
{
    const float* x  = (const float*)d_in[0];
    const float* c  = (const float*)d_in[1];
    const float* Wq = (const float*)d_in[2];
    const float* bq = (const float*)d_in[3];
    const float* Wk = (const float*)d_in[4];
    const float* bk = (const float*)d_in[5];
    const float* Wv = (const float*)d_in[6];
    const float* bv = (const float*)d_in[7];
    float* out = (float*)d_out;

    const size_t nQ = (size_t)Bb * SQn * Dd;          // 8.39M elems
    unsigned short* Qh = (unsigned short*)d_ws;        // [B*SQ, D] bf16 hi
    unsigned short* Ql = Qh + nQ;                      // lo
    unsigned short* Kh = Ql + nQ;
    unsigned short* Kl = Kh + nQ;
    unsigned short* Vt = Kl + nQ;                      // [B][D][SK] bf16
    float* S = (float*)(Vt + nQ);                      // [SQ, SK] fp32 (per batch)
    unsigned short* P = (unsigned short*)(S + (size_t)SQn*SKn);  // [SQ, SK] bf16

    const dim3 blk(256);

    gemm_proj<3,0><<<dim3(Dd/BN, (Bb*SQn)/BM), blk, 0, stream>>>(x, Wq, bq, Qh, Ql, Bb*SQn, Dd, Dd);
    gemm_proj<3,0><<<dim3(Dd/BN, (Bb*SKn)/BM), blk, 0, stream>>>(c, Wk, bk, Kh, Kl, Bb*SKn, Dd, Dd);
    gemm_proj<1,1><<<dim3(Dd/BN, (Bb*SKn)/BM), blk, 0, stream>>>(c, Wv, bv, Vt, nullptr, Bb*SKn, Dd, Dd);

    for (int b = 0; b < Bb; ++b) {
        const size_t qoff = (size_t)b * SQn * Dd;
        const size_t koff = (size_t)b * SKn * Dd;
        gemm_bf16k<3><<<dim3(SKn/BN, SQn/BM), blk, 0, stream>>>(
            Qh+qoff, Ql+qoff, Kh+koff, Kl+koff, S, SQn, SKn, Dd);
        softmax_p<<<dim3(SQn), blk, 0, stream>>>(S, P);
        gemm_bf16k<1><<<dim3(Dd/BN, SQn/BM), blk, 0, stream>>>(
            P, nullptr, Vt + (size_t)b*Dd*SKn, nullptr, out + qoff, SQn, Dd, SKn);
    }
}

// Round 3
// 493.714 us; speedup vs baseline: 3.6336x; 2.1980x over previous
//
#include <hip/hip_runtime.h>

using f32x4  = __attribute__((ext_vector_type(4))) float;
using bf16x8 = __attribute__((ext_vector_type(8))) __bf16;
using u16x4  = __attribute__((ext_vector_type(4))) unsigned short;

constexpr int Bb = 4, SQn = 2048, SKn = 2048, Dd = 1024;

__device__ __forceinline__ unsigned fbitsu(float x){ union{float f;unsigned u;}c; c.f=x; return c.u; }
__device__ __forceinline__ float ubitsf(unsigned u){ union{unsigned u;float f;}c; c.u=u; return c.f; }
__device__ __forceinline__ unsigned short hi_trunc(float x){ return (unsigned short)(fbitsu(x)>>16); }
__device__ __forceinline__ unsigned short hi_rne(float x){ unsigned u=fbitsu(x); return (unsigned short)((u + 0x7FFFu + ((u>>16)&1u))>>16); }
__device__ __forceinline__ float from_hi(unsigned short h){ return ubitsf(((unsigned)h)<<16); }

__device__ __forceinline__ f32x4 mfma_bf16(bf16x8 a, bf16x8 b, f32x4 c){
    return __builtin_amdgcn_mfma_f32_16x16x32_bf16(a, b, c, 0, 0, 0);
}

__device__ __forceinline__ void gload16(const void* g, void* l){
    __builtin_amdgcn_global_load_lds(
        (const __attribute__((address_space(1))) unsigned int*)g,
        (__attribute__((address_space(3))) unsigned int*)l, 16, 0, 0);
}

// ---------------------------------------------------------------------------
// Unified bf16 NT GEMM with global_load_lds staging.
// C[m,n] = sum_k A[m,k]*B[n,k]; TERMS=3: (Ah+Al).(Bh+Bl) dropping Al*Bl.
// 4 waves in 2x2; per-wave tile (BM_/2)x(BN_/2). fp32 output.
// ---------------------------------------------------------------------------
template<int TERMS, int BM_, int BN_, int BK_>
__global__ __launch_bounds__(256, 2)
void gemm_bf16(const unsigned short* __restrict__ Ahg, const unsigned short* __restrict__ Alg,
               const unsigned short* __restrict__ Bhg, const unsigned short* __restrict__ Blg,
               float* __restrict__ C, int M, int N, int K)
{
    constexpr int ROWB = BK_ * 2;          // bytes per LDS row
    constexpr int RPC  = 1024 / ROWB;      // rows per 1KB wave-load chunk
    constexpr int CA   = BM_ / RPC;        // chunks for A tile
    constexpr int CB   = BN_ / RPC;
    constexpr int AI   = BM_ / 32;         // per-wave 16-row frags
    constexpr int BJ   = BN_ / 32;
    constexpr int KH   = BK_ / 32;
    static_assert(CA % 4 == 0 && CB % 4 == 0, "chunk counts divisible by 4 waves");

    __shared__ __align__(16) unsigned short Ash[BM_*BK_], Bsh[BN_*BK_];
    __shared__ __align__(16) unsigned short Asl[TERMS==3?BM_*BK_:8], Bsl[TERMS==3?BN_*BK_:8];

    const int tid = threadIdx.x, lane = tid & 63, w = tid >> 6;
    const int wr = (w >> 1) * (BM_/2), wc = (w & 1) * (BN_/2);
    const int lr = lane & 15, lg = lane >> 4;
    const int m0 = blockIdx.y * BM_, n0 = blockIdx.x * BN_;
    constexpr int rsh = (ROWB == 64) ? 2 : 3;
    const int rowc = lane >> rsh;
    const int colb = (lane & ((1 << rsh) - 1)) << 4;
    const size_t rsBy = (size_t)K * 2;

    f32x4 acc[AI][BJ] = {};

    for (int k0 = 0; k0 < K; k0 += BK_) {
#pragma unroll
        for (int c4 = 0; c4 < CA/4; ++c4) {
            const int c = c4*4 + w;
            const size_t go = (size_t)(m0 + c*RPC + rowc) * rsBy + (size_t)k0*2 + colb;
            gload16((const char*)Ahg + go, (char*)Ash + c*1024);
            if (TERMS == 3) gload16((const char*)Alg + go, (char*)Asl + c*1024);
        }
#pragma unroll
        for (int c4 = 0; c4 < CB/4; ++c4) {
            const int c = c4*4 + w;
            const size_t go = (size_t)(n0 + c*RPC + rowc) * rsBy + (size_t)k0*2 + colb;
            gload16((const char*)Bhg + go, (char*)Bsh + c*1024);
            if (TERMS == 3) gload16((const char*)Blg + go, (char*)Bsl + c*1024);
        }
        __syncthreads();

#pragma unroll
        for (int kk = 0; kk < KH; ++kk) {
            bf16x8 ah[AI], bh[BJ];
#pragma unroll
            for (int i = 0; i < AI; ++i) ah[i] = *(const bf16x8*)&Ash[(wr + i*16 + lr)*BK_ + kk*32 + lg*8];
#pragma unroll
            for (int j = 0; j < BJ; ++j) bh[j] = *(const bf16x8*)&Bsh[(wc + j*16 + lr)*BK_ + kk*32 + lg*8];
            if (TERMS == 3) {
                bf16x8 al[AI], bl[BJ];
#pragma unroll
                for (int i = 0; i < AI; ++i) al[i] = *(const bf16x8*)&Asl[(wr + i*16 + lr)*BK_ + kk*32 + lg*8];
#pragma unroll
                for (int j = 0; j < BJ; ++j) bl[j] = *(const bf16x8*)&Bsl[(wc + j*16 + lr)*BK_ + kk*32 + lg*8];
#pragma unroll
                for (int i = 0; i < AI; ++i)
#pragma unroll
                    for (int j = 0; j < BJ; ++j) {
                        acc[i][j] = mfma_bf16(ah[i], bh[j], acc[i][j]);
                        acc[i][j] = mfma_bf16(ah[i], bl[j], acc[i][j]);
                        acc[i][j] = mfma_bf16(al[i], bh[j], acc[i][j]);
                    }
            } else {
#pragma unroll
                for (int i = 0; i < AI; ++i)
#pragma unroll
                    for (int j = 0; j < BJ; ++j)
                        acc[i][j] = mfma_bf16(ah[i], bh[j], acc[i][j]);
            }
        }
        __syncthreads();
    }

#pragma unroll
    for (int j = 0; j < BJ; ++j) {
        const int col = n0 + wc + j*16 + lr;
#pragma unroll
        for (int i = 0; i < AI; ++i)
#pragma unroll
            for (int r = 0; r < 4; ++r)
                C[(size_t)(m0 + wr + i*16 + lg*4 + r) * N + col] = acc[i][j][r];
    }
}

// ---------------------------------------------------------------------------
// Projection GEMM: fp32 A[M,K] . W[N,K]^T + bias, in-register hi/lo convert.
// BM=128, BN=64, BK=32; 4 waves 2x2, per-wave 64x32 (acc[4][2]).
// EPI=0: split bf16 out (O0=hi trunc, O1=residual). EPI=1: bf16 transposed
// per batch: O0[(b*Dd+col)<<11 | t], row = b*2048 + t.
// ---------------------------------------------------------------------------
template<int TERMS, int EPI>
__global__ __launch_bounds__(256, 2)
void gemm_proj(const float* __restrict__ A, const float* __restrict__ Bm,
               const float* __restrict__ bias,
               unsigned short* __restrict__ O0, unsigned short* __restrict__ O1,
               int M, int N, int K)
{
    constexpr int BM_ = 128, BN_ = 64, BK_ = 32;
    __shared__ __align__(16) unsigned short Ash[BM_*BK_], Bsh[BN_*BK_];
    __shared__ __align__(16) unsigned short Asl[TERMS==3?BM_*BK_:8], Bsl[TERMS==3?BN_*BK_:8];

    const int tid = threadIdx.x, lane = tid & 63, w = tid >> 6;
    const int wr = (w >> 1) * 64, wc = (w & 1) * 32;
    const int lr = lane & 15, lg = lane >> 4;
    const int m0 = blockIdx.y * BM_, n0 = blockIdx.x * BN_;

    f32x4 acc[4][2] = {};

    for (int k0 = 0; k0 < K; k0 += BK_) {
        float4 av[4], bv[2];
#pragma unroll
        for (int u = 0; u < 4; ++u) {
            const int f = u*256 + tid;
            av[u] = *(const float4*)(A + (size_t)(m0 + (f >> 3))*K + k0 + ((f & 7) << 2));
        }
#pragma unroll
        for (int u = 0; u < 2; ++u) {
            const int f = u*256 + tid;
            bv[u] = *(const float4*)(Bm + (size_t)(n0 + (f >> 3))*K + k0 + ((f & 7) << 2));
        }
        __syncthreads();
#pragma unroll
        for (int u = 0; u < 4; ++u) {
            const int f = u*256 + tid;
            const int row = f >> 3, ko = (f & 7) << 2;
            float a4[4]; *(float4*)a4 = av[u];
            u16x4 ah;
            if (TERMS == 3) {
                u16x4 al;
#pragma unroll
                for (int j = 0; j < 4; ++j) { ah[j] = hi_trunc(a4[j]); al[j] = hi_trunc(a4[j] - from_hi(ah[j])); }
                *(u16x4*)&Asl[row*BK_ + ko] = al;
            } else {
#pragma unroll
                for (int j = 0; j < 4; ++j) ah[j] = hi_rne(a4[j]);
            }
            *(u16x4*)&Ash[row*BK_ + ko] = ah;
        }
#pragma unroll
        for (int u = 0; u < 2; ++u) {
            const int f = u*256 + tid;
            const int row = f >> 3, ko = (f & 7) << 2;
            float b4[4]; *(float4*)b4 = bv[u];
            u16x4 bh;
            if (TERMS == 3) {
                u16x4 bl;
#pragma unroll
                for (int j = 0; j < 4; ++j) { bh[j] = hi_trunc(b4[j]); bl[j] = hi_trunc(b4[j] - from_hi(bh[j])); }
                *(u16x4*)&Bsl[row*BK_ + ko] = bl;
            } else {
#pragma unroll
                for (int j = 0; j < 4; ++j) bh[j] = hi_rne(b4[j]);
            }
            *(u16x4*)&Bsh[row*BK_ + ko] = bh;
        }
        __syncthreads();

        bf16x8 ah[4], bh[2];
#pragma unroll
        for (int i = 0; i < 4; ++i) ah[i] = *(const bf16x8*)&Ash[(wr + i*16 + lr)*BK_ + lg*8];
#pragma unroll
        for (int j = 0; j < 2; ++j) bh[j] = *(const bf16x8*)&Bsh[(wc + j*16 + lr)*BK_ + lg*8];
        if (TERMS == 3) {
            bf16x8 al[4], bl[2];
#pragma unroll
            for (int i = 0; i < 4; ++i) al[i] = *(const bf16x8*)&Asl[(wr + i*16 + lr)*BK_ + lg*8];
#pragma unroll
            for (int j = 0; j < 2; ++j) bl[j] = *(const bf16x8*)&Bsl[(wc + j*16 + lr)*BK_ + lg*8];
#pragma unroll
            for (int i = 0; i < 4; ++i)
#pragma unroll
                for (int j = 0; j < 2; ++j) {
                    acc[i][j] = mfma_bf16(ah[i], bh[j], acc[i][j]);
                    acc[i][j] = mfma_bf16(ah[i], bl[j], acc[i][j]);
                    acc[i][j] = mfma_bf16(al[i], bh[j], acc[i][j]);
                }
        } else {
#pragma unroll
            for (int i = 0; i < 4; ++i)
#pragma unroll
                for (int j = 0; j < 2; ++j)
                    acc[i][j] = mfma_bf16(ah[i], bh[j], acc[i][j]);
        }
        __syncthreads();
    }

#pragma unroll
    for (int j = 0; j < 2; ++j) {
        const int col = n0 + wc + j*16 + lr;
        const float bc = bias[col];
#pragma unroll
        for (int i = 0; i < 4; ++i) {
            if (EPI == 0) {
#pragma unroll
                for (int r = 0; r < 4; ++r) {
                    const int row = m0 + wr + i*16 + lg*4 + r;
                    const float v = acc[i][j][r] + bc;
                    const unsigned short h = hi_trunc(v);
                    O0[(size_t)row*N + col] = h;
                    O1[(size_t)row*N + col] = hi_trunc(v - from_hi(h));
                }
            } else {
                const int row0 = m0 + wr + i*16 + lg*4;
                const int b = row0 >> 11, t0 = row0 & 2047;
                u16x4 pk;
#pragma unroll
                for (int r = 0; r < 4; ++r) pk[r] = hi_rne(acc[i][j][r] + bc);
                *(u16x4*)&O0[(((size_t)b*Dd + col) << 11) + t0] = pk;
            }
        }
    }
}

// ---------------------------------------------------------------------------
// Row softmax (2048 cols), fp32 in -> bf16 out. One 256-thread block per row.
// ---------------------------------------------------------------------------
__global__ __launch_bounds__(256)
void softmax_p(const float* __restrict__ S, unsigned short* __restrict__ P)
{
    const int tid = threadIdx.x;
    const float* p = S + (size_t)blockIdx.x * SKn;
    unsigned short* o = P + (size_t)blockIdx.x * SKn;
    __shared__ float red[8];

    float4 v0 = *(const float4*)(p + tid*4);
    float4 v1 = *(const float4*)(p + 1024 + tid*4);
    float m = fmaxf(fmaxf(fmaxf(v0.x,v0.y),fmaxf(v0.z,v0.w)),
                    fmaxf(fmaxf(v1.x,v1.y),fmaxf(v1.z,v1.w)));
#pragma unroll
    for (int o2 = 32; o2 > 0; o2 >>= 1) m = fmaxf(m, __shfl_down(m, o2));
    if ((tid & 63) == 0) red[tid >> 6] = m;
    __syncthreads();
    m = fmaxf(fmaxf(red[0],red[1]), fmaxf(red[2],red[3]));

    float e[8];
    e[0]=__expf(v0.x-m); e[1]=__expf(v0.y-m); e[2]=__expf(v0.z-m); e[3]=__expf(v0.w-m);
    e[4]=__expf(v1.x-m); e[5]=__expf(v1.y-m); e[6]=__expf(v1.z-m); e[7]=__expf(v1.w-m);
    float s = ((e[0]+e[1])+(e[2]+e[3])) + ((e[4]+e[5])+(e[6]+e[7]));
#pragma unroll
    for (int o2 = 32; o2 > 0; o2 >>= 1) s += __shfl_down(s, o2);
    if ((tid & 63) == 0) red[4 + (tid >> 6)] = s;
    __syncthreads();
    const float inv = 1.f / ((red[4]+red[5])+(red[6]+red[7]));

    u16x4 p0, p1;
#pragma unroll
    for (int r = 0; r < 4; ++r) { p0[r] = hi_rne(e[r]*inv); p1[r] = hi_rne(e[4+r]*inv); }
    *(u16x4*)&o[tid*4] = p0;
    *(u16x4*)&o[1024 + tid*4] = p1;
}

extern "C" void kernel_launch(void* const* d_in, const int* in_sizes, int n_in,
                              void* d_out, int out_size, void* d_ws, size_t ws_size,
                              hipStream_t stream)
{
    const float* x  = (const float*)d_in[0];
    const float* c  = (const float*)d_in[1];
    const float* Wq = (const float*)d_in[2];
    const float* bq = (const float*)d_in[3];
    const float* Wk = (const float*)d_in[4];
    const float* bk = (const float*)d_in[5];
    const float* Wv = (const float*)d_in[6];
    const float* bv = (const float*)d_in[7];
    float* out = (float*)d_out;

    const size_t nQ = (size_t)Bb * SQn * Dd;
    unsigned short* Qh = (unsigned short*)d_ws;
    unsigned short* Ql = Qh + nQ;
    unsigned short* Kh = Ql + nQ;
    unsigned short* Kl = Kh + nQ;
    unsigned short* Vt = Kl + nQ;                     // [B][D][SK]
    float* S = (float*)(Vt + nQ);                     // [SQ,SK] fp32, per-batch
    unsigned short* P = (unsigned short*)(S + (size_t)SQn*SKn);

    const dim3 blk(256);

    gemm_proj<3,0><<<dim3(Dd/64, (Bb*SQn)/128), blk, 0, stream>>>(x, Wq, bq, Qh, Ql, Bb*SQn, Dd, Dd);
    gemm_proj<3,0><<<dim3(Dd/64, (Bb*SKn)/128), blk, 0, stream>>>(c, Wk, bk, Kh, Kl, Bb*SKn, Dd, Dd);
    gemm_proj<1,1><<<dim3(Dd/64, (Bb*SKn)/128), blk, 0, stream>>>(c, Wv, bv, Vt, nullptr, Bb*SKn, Dd, Dd);

    for (int b = 0; b < Bb; ++b) {
        const size_t qoff = (size_t)b * SQn * Dd;
        const size_t koff = (size_t)b * SKn * Dd;
        gemm_bf16<3,128,64,32><<<dim3(SKn/64, SQn/128), blk, 0, stream>>>(
            Qh+qoff, Ql+qoff, Kh+koff, Kl+koff, S, SQn, SKn, Dd);
        softmax_p<<<dim3(SQn), blk, 0, stream>>>(S, P);
        gemm_bf16<1,64,64,64><<<dim3(Dd/64, SQn/64), blk, 0, stream>>>(
            P, nullptr, Vt + (size_t)b*Dd*SKn, nullptr, out + qoff, SQn, Dd, SKn);
    }
}